// Round 12
// baseline (515.945 us; speedup 1.0000x reference)
//
#include <hip/hip_runtime.h>
#include <hip/hip_bf16.h>

#define M_DIM 8192
#define N_DIM 11008
#define K_DIM 4096
#define NTL 64                       // K-tiles of BK=64 (int8)
#define RROW ((size_t)64 * K_DIM)    // 64 rows of int8, in bytes

typedef __attribute__((ext_vector_type(4))) int i32x4;

// ---------------- per-token activation quant: n = rint(x/s), s = max(absmax,1e-5)/7 ----------------
__global__ void quant_x_kernel(const float* __restrict__ x,
                               char* __restrict__ xq, float* __restrict__ sx) {
  const int row = blockIdx.x;      // 8192
  const int t = threadIdx.x;       // 256
  const float4* xr4 = (const float4*)(x + (size_t)row * K_DIM);
  float4 v[4];
  float amax = 0.0f;
#pragma unroll
  for (int i = 0; i < 4; ++i) {
    v[i] = xr4[t + 256 * i];
    amax = fmaxf(amax, fmaxf(fmaxf(fabsf(v[i].x), fabsf(v[i].y)),
                             fmaxf(fabsf(v[i].z), fabsf(v[i].w))));
  }
#pragma unroll
  for (int off = 32; off > 0; off >>= 1)
    amax = fmaxf(amax, __shfl_xor(amax, off, 64));
  __shared__ float red[4];
  if ((t & 63) == 0) red[t >> 6] = amax;
  __syncthreads();
  amax = fmaxf(fmaxf(red[0], red[1]), fmaxf(red[2], red[3]));
  const float s = fmaxf(amax, 1e-5f) / 7.0f;   // matches reference bitwise
  if (t == 0) sx[row] = s;
  char q[16];
#pragma unroll
  for (int i = 0; i < 4; ++i) {
    q[i * 4 + 0] = (char)(int)rintf(v[i].x / s);  // RNE, exact ints in [-7,7]
    q[i * 4 + 1] = (char)(int)rintf(v[i].y / s);
    q[i * 4 + 2] = (char)(int)rintf(v[i].z / s);
    q[i * 4 + 3] = (char)(int)rintf(v[i].w / s);
  }
  *(int4*)(xq + (size_t)row * K_DIM + t * 16) = *(int4*)q;
}

// ---------------- per-output-channel weight quant: int8 / 127 (row-major) ----------------
__global__ void quant_w_kernel(const float* __restrict__ w,
                               char* __restrict__ wq, float* __restrict__ sw) {
  const int row = blockIdx.x;      // 11008
  const int t = threadIdx.x;       // 256
  const float4* wr4 = (const float4*)(w + (size_t)row * K_DIM);
  float4 v[4];
  float amax = 0.0f;
#pragma unroll
  for (int i = 0; i < 4; ++i) {
    v[i] = wr4[t + 256 * i];
    amax = fmaxf(amax, fmaxf(fmaxf(fabsf(v[i].x), fabsf(v[i].y)),
                             fmaxf(fabsf(v[i].z), fabsf(v[i].w))));
  }
#pragma unroll
  for (int off = 32; off > 0; off >>= 1)
    amax = fmaxf(amax, __shfl_xor(amax, off, 64));
  __shared__ float red[4];
  if ((t & 63) == 0) red[t >> 6] = amax;
  __syncthreads();
  amax = fmaxf(fmaxf(red[0], red[1]), fmaxf(red[2], red[3]));
  const float s = fmaxf(amax, 1e-30f) / 127.0f;
  if (t == 0) sw[row] = s;
  char q[16];
#pragma unroll
  for (int i = 0; i < 4; ++i) {
    q[i * 4 + 0] = (char)(int)rintf(v[i].x / s);  // in [-127,127]
    q[i * 4 + 1] = (char)(int)rintf(v[i].y / s);
    q[i * 4 + 2] = (char)(int)rintf(v[i].z / s);
    q[i * 4 + 3] = (char)(int)rintf(v[i].w / s);
  }
  *(int4*)(wq + (size_t)row * K_DIM + t * 16) = *(int4*)q;
}

// ---------------- GEMM ----------------
// 128x256 tile, BK=64 int8, 256 thr (4 waves, wave w = 64-col slice), dbuf LDS
// 48 KiB -> 2 INDEPENDENT blocks/CU: their barrier groups are unsynchronized,
// so one block's MFMA bursts cover the other's read/barrier windows (m114).
// BK=64 rows are 64 B, so every fragment-read's wave footprint is a contiguous
// 1 KB LDS region -> conflict-free with NO swizzle; staging is linear.
// Loose R6-style tile body (1 __syncthreads/tile; compiler-counted lgkm waits).
#define GL(g, d)                                                             \
  __builtin_amdgcn_global_load_lds(                                          \
      (const __attribute__((address_space(1))) void*)(g),                    \
      (__attribute__((address_space(3))) void*)(d), 16, 0, 0)

#define MFMA_I8 __builtin_amdgcn_mfma_i32_16x16x64_i8

template<bool STG>
__device__ __forceinline__ void tile_body(const char* pa, const char* pb,
    const char* gA1, char* dA1, const char* gB1, char* dB1, i32x4 (&acc)[8][4]) {
  __syncthreads();   // tile t staged (syncthreads drains vmcnt); prev readers done
  if constexpr (STG) {  // stage tile t+1 into the other buffer (linear)
    GL(gA1, dA1);              GL(gA1 + RROW, dA1 + 4096);
    GL(gB1, dB1);              GL(gB1 + RROW, dB1 + 4096);
    GL(gB1 + 2 * RROW, dB1 + 8192); GL(gB1 + 3 * RROW, dB1 + 12288);
  }
  i32x4 a[8], b[4];
  // seg1: B + A(m0-3) reads
#pragma unroll
  for (int n = 0; n < 4; ++n) b[n] = *(const i32x4*)(pb + n * 1024);
#pragma unroll
  for (int m = 0; m < 4; ++m) a[m] = *(const i32x4*)(pa + m * 1024);
  __builtin_amdgcn_sched_barrier(0);
  // seg2: A(m4-7) reads || MFMA m0-3
#pragma unroll
  for (int m = 4; m < 8; ++m) a[m] = *(const i32x4*)(pa + m * 1024);
#pragma unroll
  for (int m = 0; m < 4; ++m)
#pragma unroll
    for (int n = 0; n < 4; ++n)
      acc[m][n] = MFMA_I8(a[m], b[n], acc[m][n], 0, 0, 0);
  __builtin_amdgcn_sched_barrier(0);
  // seg3: MFMA m4-7 (other block's reads overlap this on the CU)
#pragma unroll
  for (int m = 4; m < 8; ++m)
#pragma unroll
    for (int n = 0; n < 4; ++n)
      acc[m][n] = MFMA_I8(a[m], b[n], acc[m][n], 0, 0, 0);
}

__global__ __launch_bounds__(256, 2) void gemm_kernel(
    const char* __restrict__ xq, const char* __restrict__ wq,
    const float* __restrict__ sx, const float* __restrict__ sw,
    const float* __restrict__ bias, float* __restrict__ out) {
  __shared__ char lds_c[49152];  // A: [0,16K) bufs 8K x2; B: [16K,48K) bufs 16K x2

  const int tid = threadIdx.x;
  const int lane = tid & 63;
  const int wave = tid >> 6;      // 0..3 = 64-col slice
  const int lr = lane & 15;
  const int hi = lane >> 4;

  // bm-fastest bijective XCD swizzle (2752 = 8*344): co-resident blocks of an
  // XCD share one ~1 MB B-panel (L2-hot); A panels stream via L3.
  const int bid = blockIdx.x;
  const int sw_id = (bid & 7) * 344 + (bid >> 3);
  const int bm = sw_id & 63, bn = sw_id >> 6;
  const int m0 = bm * 128, n0 = bn * 256;

  // staging: thread t -> row t>>2 (0..63), colbyte (t&3)*16; round r adds 64 rows
  const int srow = tid >> 2;
  const int scol = (tid & 3) << 4;
  const char* gA0 = xq + (size_t)(m0 + srow) * K_DIM + scol;
  const char* gB0 = wq + (size_t)(n0 + srow) * K_DIM + scol;
  char* dA0 = lds_c + wave * 1024;             // wave-uniform; HW adds lane*16
  char* dB0 = lds_c + 16384 + wave * 1024;

  // read bases (linear, conflict-free at BK=64)
  const char* pa0 = lds_c + lr * 64 + hi * 16;                       // + m*1024
  const char* pb0 = lds_c + 16384 + (wave * 64 + lr) * 64 + hi * 16; // + n*1024

  i32x4 acc[8][4] = {};

  // prologue: stage tile 0 into buf 0
  GL(gA0, dA0);              GL(gA0 + RROW, dA0 + 4096);
  GL(gB0, dB0);              GL(gB0 + RROW, dB0 + 4096);
  GL(gB0 + 2 * RROW, dB0 + 8192); GL(gB0 + 3 * RROW, dB0 + 12288);

  for (int t = 0; t < NTL - 1; ++t) {
    const int buf = t & 1;
    tile_body<true>(pa0 + buf * 8192, pb0 + buf * 16384,
                    gA0 + (size_t)(t + 1) * 64, dA0 + (1 - buf) * 8192,
                    gB0 + (size_t)(t + 1) * 64, dB0 + (1 - buf) * 16384, acc);
  }
  tile_body<false>(pa0 + ((NTL - 1) & 1) * 8192, pb0 + ((NTL - 1) & 1) * 16384,
                   nullptr, nullptr, nullptr, nullptr, acc);

  // epilogue: C/D layout col=lane&15, row=(lane>>4)*4+reg (dtype-independent)
  const int orow0 = m0 + (lane >> 4) * 4;
  const int ocol0 = n0 + wave * 64 + lr;
  float bv[4], swv[4];
#pragma unroll
  for (int fc = 0; fc < 4; ++fc) {
    bv[fc] = bias[ocol0 + fc * 16];
    swv[fc] = sw[ocol0 + fc * 16];
  }
#pragma unroll
  for (int fr = 0; fr < 8; ++fr) {
#pragma unroll
    for (int j = 0; j < 4; ++j) {
      const int grow = orow0 + fr * 16 + j;
      const float s = sx[grow];
      float* op = out + (size_t)grow * N_DIM + ocol0;
#pragma unroll
      for (int fc = 0; fc < 4; ++fc)
        op[fc * 16] = (float)acc[fr][fc][j] * (s * swv[fc]) + bv[fc];
    }
  }
}

extern "C" void kernel_launch(void* const* d_in, const int* in_sizes, int n_in,
                              void* d_out, int out_size, void* d_ws, size_t ws_size,
                              hipStream_t stream) {
  (void)in_sizes; (void)n_in; (void)out_size; (void)ws_size;
  const float* x = (const float*)d_in[0];       // [4,2048,4096] f32
  const float* w = (const float*)d_in[1];       // [11008,4096] f32
  const float* bias = (const float*)d_in[2];    // [1,11008] f32
  float* out = (float*)d_out;                   // [8192,11008] f32

  char* ws = (char*)d_ws;
  float* sx = (float*)ws;                                   // 32 KiB
  float* sw = (float*)(ws + 32768);                         // 44 KiB
  char* xq8 = ws + 131072;                                  // 32 MiB int8
  char* wq8 = ws + 131072 + (size_t)M_DIM * K_DIM;          // 43 MiB int8

  quant_x_kernel<<<M_DIM, 256, 0, stream>>>(x, xq8, sx);
  quant_w_kernel<<<N_DIM, 256, 0, stream>>>(w, wq8, sw);
  gemm_kernel<<<dim3((M_DIM / 128) * (N_DIM / 256)), 256, 0, stream>>>(xq8, wq8, sx, sw, bias, out);
}

// Round 13
// 491.977 us; speedup vs baseline: 1.0487x; 1.0487x over previous
//
#include <hip/hip_runtime.h>
#include <hip/hip_bf16.h>

#define M_DIM 8192
#define N_DIM 11008
#define K_DIM 4096
#define NT 32                        // K-tiles of BK=128 (int8)
#define RROW ((size_t)64 * K_DIM)    // 64 rows of int8, in bytes

typedef __attribute__((ext_vector_type(4))) int i32x4;
typedef __attribute__((ext_vector_type(16))) int i32x16;

// ---------------- per-token activation quant: n = rint(x/s), s = max(absmax,1e-5)/7 ----------------
__global__ void quant_x_kernel(const float* __restrict__ x,
                               char* __restrict__ xq, float* __restrict__ sx) {
  const int row = blockIdx.x;      // 8192
  const int t = threadIdx.x;       // 256
  const float4* xr4 = (const float4*)(x + (size_t)row * K_DIM);
  float4 v[4];
  float amax = 0.0f;
#pragma unroll
  for (int i = 0; i < 4; ++i) {
    v[i] = xr4[t + 256 * i];
    amax = fmaxf(amax, fmaxf(fmaxf(fabsf(v[i].x), fabsf(v[i].y)),
                             fmaxf(fabsf(v[i].z), fabsf(v[i].w))));
  }
#pragma unroll
  for (int off = 32; off > 0; off >>= 1)
    amax = fmaxf(amax, __shfl_xor(amax, off, 64));
  __shared__ float red[4];
  if ((t & 63) == 0) red[t >> 6] = amax;
  __syncthreads();
  amax = fmaxf(fmaxf(red[0], red[1]), fmaxf(red[2], red[3]));
  const float s = fmaxf(amax, 1e-5f) / 7.0f;   // matches reference bitwise
  if (t == 0) sx[row] = s;
  char q[16];
#pragma unroll
  for (int i = 0; i < 4; ++i) {
    q[i * 4 + 0] = (char)(int)rintf(v[i].x / s);  // RNE, exact ints in [-7,7]
    q[i * 4 + 1] = (char)(int)rintf(v[i].y / s);
    q[i * 4 + 2] = (char)(int)rintf(v[i].z / s);
    q[i * 4 + 3] = (char)(int)rintf(v[i].w / s);
  }
  *(int4*)(xq + (size_t)row * K_DIM + t * 16) = *(int4*)q;
}

// ---------------- per-output-channel weight quant: int8 / 127 (row-major) ----------------
__global__ void quant_w_kernel(const float* __restrict__ w,
                               char* __restrict__ wq, float* __restrict__ sw) {
  const int row = blockIdx.x;      // 11008
  const int t = threadIdx.x;       // 256
  const float4* wr4 = (const float4*)(w + (size_t)row * K_DIM);
  float4 v[4];
  float amax = 0.0f;
#pragma unroll
  for (int i = 0; i < 4; ++i) {
    v[i] = wr4[t + 256 * i];
    amax = fmaxf(amax, fmaxf(fmaxf(fabsf(v[i].x), fabsf(v[i].y)),
                             fmaxf(fabsf(v[i].z), fabsf(v[i].w))));
  }
#pragma unroll
  for (int off = 32; off > 0; off >>= 1)
    amax = fmaxf(amax, __shfl_xor(amax, off, 64));
  __shared__ float red[4];
  if ((t & 63) == 0) red[t >> 6] = amax;
  __syncthreads();
  amax = fmaxf(fmaxf(red[0], red[1]), fmaxf(red[2], red[3]));
  const float s = fmaxf(amax, 1e-30f) / 127.0f;
  if (t == 0) sw[row] = s;
  char q[16];
#pragma unroll
  for (int i = 0; i < 4; ++i) {
    q[i * 4 + 0] = (char)(int)rintf(v[i].x / s);  // in [-127,127]
    q[i * 4 + 1] = (char)(int)rintf(v[i].y / s);
    q[i * 4 + 2] = (char)(int)rintf(v[i].z / s);
    q[i * 4 + 3] = (char)(int)rintf(v[i].w / s);
  }
  *(int4*)(wq + (size_t)row * K_DIM + t * 16) = *(int4*)q;
}

// ---------------- GEMM ----------------
// R6 chassis + mfma_i32_32x32x32_i8 (single-variable change vs R6):
// 256x256 tile, BK=128 int8, 512 thr (8 waves 2x4), ring-2 LDS 128 KiB,
// 1 __syncthreads/tile, sched_barrier(0) segments {read ks+1 || MFMA ks}.
// Per wave: 4 m-blocks x 2 n-blocks of 32x32, K = 4 slices of 32; 32 MFMA/tile
// (was 64 of 16x16x64) at the 4404-TOPS 32x32 rate (was 3944).
// LDS image & staging identical to R6 (swizzle phys = row*128 + (col ^ ((row&7)<<4))).
// Frag read: row = base + (lane&31); colphys = ((l>>5)<<4 ^ (l&7)<<4) ^ (ks<<5).
#define GL(g, d)                                                             \
  __builtin_amdgcn_global_load_lds(                                          \
      (const __attribute__((address_space(1))) void*)(g),                    \
      (__attribute__((address_space(3))) void*)(d), 16, 0, 0)

#define MFMA32 __builtin_amdgcn_mfma_i32_32x32x32_i8

#define STAGE4(g, d)                                       \
  do {                                                     \
    GL((g), (d));                                          \
    GL((g) + RROW, (d) + 8192);                            \
    GL((g) + 2 * RROW, (d) + 16384);                       \
    GL((g) + 3 * RROW, (d) + 24576);                       \
  } while (0)

__device__ __forceinline__ void rd_ab(const char* paRow, const char* pbRow, int c,
                                      i32x4 (&a)[4], i32x4 (&b)[2]) {
#pragma unroll
  for (int mb = 0; mb < 4; ++mb) a[mb] = *(const i32x4*)(paRow + mb * 4096 + c);
#pragma unroll
  for (int nb = 0; nb < 2; ++nb) b[nb] = *(const i32x4*)(pbRow + nb * 4096 + c);
}
__device__ __forceinline__ void mfma8(const i32x4 (&a)[4], const i32x4 (&b)[2],
                                      i32x16 (&acc)[4][2]) {
#pragma unroll
  for (int mb = 0; mb < 4; ++mb)
#pragma unroll
    for (int nb = 0; nb < 2; ++nb)
      acc[mb][nb] = MFMA32(a[mb], b[nb], acc[mb][nb], 0, 0, 0);
}

template<bool STG>
__device__ __forceinline__ void tile_body(const char* paRow, const char* pbRow,
    const int (&c)[4], const char* gA1, char* dA1, const char* gB1, char* dB1,
    i32x16 (&acc)[4][2]) {
  __syncthreads();   // tile t staged (drains vmcnt); prev-buffer readers done
  if constexpr (STG) {  // stage tile t+1 into the other buffer
    STAGE4(gA1, dA1);
    STAGE4(gB1, dB1);
  }
  i32x4 a0[4], b0[2], a1[4], b1[2];
  // seg1: reads ks0
  rd_ab(paRow, pbRow, c[0], a0, b0);
  __builtin_amdgcn_sched_barrier(0);
  // seg2: reads ks1 || MFMA ks0
  rd_ab(paRow, pbRow, c[1], a1, b1);
  mfma8(a0, b0, acc);
  __builtin_amdgcn_sched_barrier(0);
  // seg3: reads ks2 || MFMA ks1
  rd_ab(paRow, pbRow, c[2], a0, b0);
  mfma8(a1, b1, acc);
  __builtin_amdgcn_sched_barrier(0);
  // seg4: reads ks3 || MFMA ks2
  rd_ab(paRow, pbRow, c[3], a1, b1);
  mfma8(a0, b0, acc);
  __builtin_amdgcn_sched_barrier(0);
  // seg5: MFMA ks3
  mfma8(a1, b1, acc);
}

__global__ __launch_bounds__(512, 2) void gemm_kernel(
    const char* __restrict__ xq, const char* __restrict__ wq,
    const float* __restrict__ sx, const float* __restrict__ sw,
    const float* __restrict__ bias, float* __restrict__ out) {
  __shared__ char lds_c[131072];  // A: [0,64K) bufs 0/1; B: [64K,128K) bufs 0/1

  const int tid = threadIdx.x;
  const int lane = tid & 63;
  const int wave = tid >> 6;
  const int wm = wave >> 2;       // 0..1
  const int wn = wave & 3;        // 0..3
  const int l31 = lane & 31;
  const int hi5 = lane >> 5;

  // T1: bijective XCD swizzle (1376 = 8*172), R6 mapping
  const int bid = blockIdx.x;
  const int sw_id = (bid & 7) * 172 + (bid >> 3);
  const int bm = sw_id / 43, bn = sw_id % 43;
  const int m0 = bm * 256, n0 = bn * 256;

  // staging source (inverse swizzle, rule #21) — identical LDS image to R6
  const int srow = tid >> 3;
  const int srccb = ((tid & 7) << 4) ^ ((srow & 7) << 4);
  const char* gA0 = xq + (size_t)(m0 + srow) * K_DIM + srccb;
  const char* gB0 = wq + (size_t)(n0 + srow) * K_DIM + srccb;
  char* dA0 = lds_c + wave * 1024;            // wave-uniform; HW adds lane*16
  char* dB0 = lds_c + 65536 + wave * 1024;

  // read-side bases: row = base + (lane&31); col = (hi5*16 ^ (l&7)*16) ^ ks*32
  const int aRowOff = (wm * 128 + l31) * 128;
  const int bRowOff = (wn * 64 + l31) * 128;
  const int cs0 = (hi5 << 4) ^ ((lane & 7) << 4);
  const int c[4] = {cs0, cs0 ^ 32, cs0 ^ 64, cs0 ^ 96};

  i32x16 acc[4][2] = {};

  // prologue: stage tile 0 into buf 0
  STAGE4(gA0, dA0);
  STAGE4(gB0, dB0);

  for (int t = 0; t < NT - 1; ++t) {
    const int buf = t & 1;
    tile_body<true>(lds_c + buf * 32768 + aRowOff,
                    lds_c + 65536 + buf * 32768 + bRowOff, c,
                    gA0 + (size_t)(t + 1) * 128, dA0 + (1 - buf) * 32768,
                    gB0 + (size_t)(t + 1) * 128, dB0 + (1 - buf) * 32768, acc);
  }
  tile_body<false>(lds_c + ((NT - 1) & 1) * 32768 + aRowOff,
                   lds_c + 65536 + ((NT - 1) & 1) * 32768 + bRowOff, c,
                   nullptr, nullptr, nullptr, nullptr, acc);

  // epilogue: 32x32 C/D layout (m74/m101, dtype-independent):
  // row(A-side) = (reg&3) + 8*(reg>>2) + 4*(lane>>5); col(B-side) = lane&31
  const int orow0 = m0 + wm * 128 + 4 * hi5;
  const int ocol0 = n0 + wn * 64 + l31;
#pragma unroll
  for (int mb = 0; mb < 4; ++mb) {
#pragma unroll
    for (int nb = 0; nb < 2; ++nb) {
      const int ocol = ocol0 + nb * 32;
      const float swn = sw[ocol];
      const float bvn = bias[ocol];
#pragma unroll
      for (int r = 0; r < 16; ++r) {
        const int grow = orow0 + mb * 32 + (r & 3) + 8 * (r >> 2);
        const float s = sx[grow];
        out[(size_t)grow * N_DIM + ocol] = (float)acc[mb][nb][r] * (s * swn) + bvn;
      }
    }
  }
}

extern "C" void kernel_launch(void* const* d_in, const int* in_sizes, int n_in,
                              void* d_out, int out_size, void* d_ws, size_t ws_size,
                              hipStream_t stream) {
  (void)in_sizes; (void)n_in; (void)out_size; (void)ws_size;
  const float* x = (const float*)d_in[0];       // [4,2048,4096] f32
  const float* w = (const float*)d_in[1];       // [11008,4096] f32
  const float* bias = (const float*)d_in[2];    // [1,11008] f32
  float* out = (float*)d_out;                   // [8192,11008] f32

  char* ws = (char*)d_ws;
  float* sx = (float*)ws;                                   // 32 KiB
  float* sw = (float*)(ws + 32768);                         // 44 KiB
  char* xq8 = ws + 131072;                                  // 32 MiB int8
  char* wq8 = ws + 131072 + (size_t)M_DIM * K_DIM;          // 43 MiB int8

  quant_x_kernel<<<M_DIM, 256, 0, stream>>>(x, xq8, sx);
  quant_w_kernel<<<N_DIM, 256, 0, stream>>>(w, wq8, sw);
  gemm_kernel<<<dim3((M_DIM / 256) * (N_DIM / 256)), 512, 0, stream>>>(xq8, wq8, sx, sw, bias, out);
}